// Round 11
// baseline (386.357 us; speedup 1.0000x reference)
//
#include <hip/hip_runtime.h>
#include <hip/hip_bf16.h>
#include <math.h>

#define BB   8
#define LL   2048
#define DD   1024
#define HH   16
#define DKK  64
#define TOPK 7

typedef unsigned short u16;
typedef short short8 __attribute__((ext_vector_type(8)));
typedef short s4v    __attribute__((ext_vector_type(4)));
typedef float f32x4  __attribute__((ext_vector_type(4)));
typedef int   int4v  __attribute__((ext_vector_type(4)));

// ---- workspace layout (BYTE offsets), high-water = 209,715,200 B ----
#define QXH_B   0ull            // 16MB i8 q-hi   | later: PART (8.45MB)
#define QXL_B   16777216ull     // 16MB i8 q-lo   | later: TOPW/TOPI
#define KXH_B   33554432ull     // 16MB i8 k-hi
#define KXL_B   50331648ull     // 16MB i8 k-lo
#define VXH_B   67108864ull     // 32MB bf16 value
#define QWH_B   100663296ull    // 1MB
#define QWL_B   101711872ull    // 1MB
#define KWH_B   102760448ull    // 1MB
#define KWL_B   103809024ull    // 1MB
#define VWH_B   104857600ull    // 2MB
#define OWH_B   106954752ull    // 2MB
#define QTB_B   109051904ull    // 32MB bf16 qT (B,D,L) | later: aggrow
#define KTB_B   142606336ull    // 32MB bf16 kT
#define VBF_B   176160768ull    // 32MB bf16 v (B,D,L); ends 209,715,200
#define PART_B  0ull
#define PART_STRIDE 2064
#define TOPW_B  16777216ull
#define TOPI_B  16780800ull

// fixed-point scales: x on +-6 (16-bit), W on +-0.1875 (16-bit)
#define SX_INV  5461.3333f
#define SW_INV  174762.67f
#define CS1     6.8664551e-5f   // 65536 * sx * sw
#define CS2     2.6822090e-7f   // 256 * sx * sw

// XCD-aware bijective block swizzle (1024 blocks, 1024%8==0).
__device__ __forceinline__ int2 xcd_swizzle_8x128() {
    const int lin = blockIdx.y * gridDim.x + blockIdx.x;   // [0,1024)
    const int swz = (lin & 7) * 128 + (lin >> 3);
    return make_int2(swz & 7, swz >> 3);                   // (n-tile, m-tile)
}

// ---------------------------------------------------------------------------
// helpers
// ---------------------------------------------------------------------------
__device__ __forceinline__ u16 f2bf(float f) {
    unsigned u = __float_as_uint(f);
    unsigned r = u + 0x7FFFu + ((u >> 16) & 1u);
    return (u16)(r >> 16);
}
__device__ __forceinline__ float bf2f(u16 h) {
    return __uint_as_float((unsigned)h << 16);
}

// 4 elems/thread, fully lane-contiguous: float4 load, char4-packed dual store
__device__ __forceinline__ void split4_i8(const float* __restrict__ x,
                                          char* __restrict__ hi,
                                          char* __restrict__ lo,
                                          float inv_s, size_t i) {
    float4 t = ((const float4*)x)[i];
    float f[4] = {t.x, t.y, t.z, t.w};
    unsigned hp = 0, lp = 0;
    #pragma unroll
    for (int j = 0; j < 4; ++j) {
        int q = __float2int_rn(f[j] * inv_s);
        q = min(max(q, -32639), 32639);
        int xl = ((q + 128) & 255) - 128;
        int xh = (q - xl) >> 8;
        hp |= ((unsigned)(xh & 255)) << (8 * j);
        lp |= ((unsigned)(xl & 255)) << (8 * j);
    }
    ((unsigned*)hi)[i] = hp;
    ((unsigned*)lo)[i] = lp;
}

// 4 elems/thread: float4 load -> short4 bf16 store (8B, lane-contiguous)
__device__ __forceinline__ void cvt4_bf(const float* __restrict__ x,
                                        u16* __restrict__ o, size_t i) {
    float4 t = ((const float4*)x)[i];
    s4v h;
    h[0] = (short)f2bf(t.x); h[1] = (short)f2bf(t.y);
    h[2] = (short)f2bf(t.z); h[3] = (short)f2bf(t.w);
    *(s4v*)(o + i * 4) = h;
}

// ---------------------------------------------------------------------------
// ALL conversions, one launch, 4 elems/thread, fully coalesced.
// blocks: [0,16384) q | [16384,32768) k | [32768,49152) v |
//         [49152,50176) Wq | [50176,51200) Wk | [51200,52224) Wv | [52224,53248) Wo
// ---------------------------------------------------------------------------
__global__ __launch_bounds__(256) void k_conv_all(
    const float* __restrict__ q, const float* __restrict__ k,
    const float* __restrict__ v,
    const float* __restrict__ Wq, const float* __restrict__ Wk,
    const float* __restrict__ Wv, const float* __restrict__ Wo,
    char* __restrict__ qh, char* __restrict__ ql,
    char* __restrict__ kh, char* __restrict__ kl, u16* __restrict__ vx,
    char* __restrict__ qwh, char* __restrict__ qwl,
    char* __restrict__ kwh, char* __restrict__ kwl,
    u16* __restrict__ vwh, u16* __restrict__ owh)
{
    const int b = blockIdx.x;
    const int t = threadIdx.x;
    if (b < 16384) {
        split4_i8(q, qh, ql, SX_INV, (size_t)b * 256 + t);
    } else if (b < 32768) {
        split4_i8(k, kh, kl, SX_INV, (size_t)(b - 16384) * 256 + t);
    } else if (b < 49152) {
        cvt4_bf(v, vx, (size_t)(b - 32768) * 256 + t);
    } else if (b < 50176) {
        split4_i8(Wq, qwh, qwl, SW_INV, (size_t)(b - 49152) * 256 + t);
    } else if (b < 51200) {
        split4_i8(Wk, kwh, kwl, SW_INV, (size_t)(b - 50176) * 256 + t);
    } else if (b < 52224) {
        cvt4_bf(Wv, vwh, (size_t)(b - 51200) * 256 + t);
    } else {
        cvt4_bf(Wo, owh, (size_t)(b - 52224) * 256 + t);
    }
}

// ---------------------------------------------------------------------------
// async global->LDS (16B, wave-uniform LDS base + lane*16)
// ---------------------------------------------------------------------------
__device__ __forceinline__ void async16(u16* l, const u16* g) {
    __builtin_amdgcn_global_load_lds(
        (const __attribute__((address_space(1))) void*)g,
        (__attribute__((address_space(3))) void*)l, 16, 0, 0);
}
__device__ __forceinline__ void async16b(char* l, const char* g) {
    __builtin_amdgcn_global_load_lds(
        (const __attribute__((address_space(1))) void*)g,
        (__attribute__((address_space(3))) void*)l, 16, 0, 0);
}

// ---------------------------------------------------------------------------
// i8-split MFMA GEMM (Q/K projections): C = A*B^T on 16-bit grids split into
// hi/lo int8; output bf16 TRANSPOSED (B,N,L) + bias.
// ---------------------------------------------------------------------------
__global__ __launch_bounds__(256, 2) void gemm_i8split(
    const char* __restrict__ Ah, const char* __restrict__ Al,
    const char* __restrict__ Bh, const char* __restrict__ Bl,
    const float* __restrict__ bias, u16* __restrict__ outb)
{
    __shared__ __align__(16) char lds[2][4][8192];   // [buf][Ah,Bh,Al,Bl][128*64]
    const int t = threadIdx.x;
    const int w = t >> 6, lane = t & 63;
    const int2 tb = xcd_swizzle_8x128();
    const int m0 = tb.y * 128, n0 = tb.x * 128;
    const int srow = lane >> 2, sslot = lane & 3;
    const int r15 = lane & 15, kg = lane >> 4;
    const int wr = w >> 1, wc = w & 1;
    const int r4 = (lane >> 4) * 4;
    const int swzb = (kg ^ (r15 & 3)) << 4;              // byte slot
    const int a_off = (wr * 64 + r15) * 64 + swzb;
    const int b_off = (wc * 64 + r15) * 64 + swzb;

    int4v acc1[4][4], acc2[4][4];
    #pragma unroll
    for (int i = 0; i < 4; ++i)
        #pragma unroll
        for (int j = 0; j < 4; ++j) {
            acc1[i][j] = (int4v){0,0,0,0};
            acc2[i][j] = (int4v){0,0,0,0};
        }

    #define STAGE8(buf, kt)                                                       \
    {                                                                             \
        const int gc0 = (kt) * 64;                                                \
        _Pragma("unroll")                                                         \
        for (int i = 0; i < 2; ++i) {                                             \
            const int row  = w * 32 + i * 16 + srow;                              \
            const int kch  = (sslot ^ (row & 3)) << 4;                            \
            const int loff = w * 2048 + i * 1024;                                 \
            async16b(&lds[buf][0][loff], Ah + (size_t)(m0 + row) * 1024 + gc0 + kch); \
            async16b(&lds[buf][1][loff], Bh + (size_t)(n0 + row) * 1024 + gc0 + kch); \
            async16b(&lds[buf][2][loff], Al + (size_t)(m0 + row) * 1024 + gc0 + kch); \
            async16b(&lds[buf][3][loff], Bl + (size_t)(n0 + row) * 1024 + gc0 + kch); \
        }                                                                         \
    }

    #define COMP8(buf)                                                            \
    {                                                                             \
        const char* cb = &lds[buf][0][0];                                         \
        int4v ah[4], bh4[4], al[4], bl[4];                                        \
        _Pragma("unroll")                                                         \
        for (int mi = 0; mi < 4; ++mi) ah[mi] = *(const int4v*)(cb + a_off + mi * 1024); \
        _Pragma("unroll")                                                         \
        for (int nj = 0; nj < 4; ++nj) bh4[nj] = *(const int4v*)(cb + 8192 + b_off + nj * 1024); \
        _Pragma("unroll")                                                         \
        for (int mi = 0; mi < 4; ++mi)                                            \
            _Pragma("unroll")                                                     \
            for (int nj = 0; nj < 4; ++nj)                                        \
                acc1[mi][nj] = __builtin_amdgcn_mfma_i32_16x16x64_i8(ah[mi], bh4[nj], acc1[mi][nj], 0, 0, 0); \
        _Pragma("unroll")                                                         \
        for (int nj = 0; nj < 4; ++nj) bl[nj] = *(const int4v*)(cb + 24576 + b_off + nj * 1024); \
        _Pragma("unroll")                                                         \
        for (int mi = 0; mi < 4; ++mi)                                            \
            _Pragma("unroll")                                                     \
            for (int nj = 0; nj < 4; ++nj)                                        \
                acc2[mi][nj] = __builtin_amdgcn_mfma_i32_16x16x64_i8(ah[mi], bl[nj], acc2[mi][nj], 0, 0, 0); \
        _Pragma("unroll")                                                         \
        for (int mi = 0; mi < 4; ++mi) al[mi] = *(const int4v*)(cb + 16384 + a_off + mi * 1024); \
        _Pragma("unroll")                                                         \
        for (int mi = 0; mi < 4; ++mi)                                            \
            _Pragma("unroll")                                                     \
            for (int nj = 0; nj < 4; ++nj)                                        \
                acc2[mi][nj] = __builtin_amdgcn_mfma_i32_16x16x64_i8(al[mi], bh4[nj], acc2[mi][nj], 0, 0, 0); \
    }

    STAGE8(0, 0);
    __syncthreads();
    int cur = 0;
    for (int kt = 0; kt < 15; ++kt) {
        STAGE8(cur ^ 1, kt + 1);
        COMP8(cur);
        __syncthreads();
        cur ^= 1;
    }
    COMP8(cur);

    // epilogue: bf16 transposed (B,N,L) + bias
    #pragma unroll
    for (int nj = 0; nj < 4; ++nj) {
        const int n = n0 + wc * 64 + nj * 16 + r15;
        const float bs = bias[n];
        #pragma unroll
        for (int mi = 0; mi < 4; ++mi) {
            const int m = m0 + wr * 64 + mi * 16 + r4;
            const int b = m >> 11;
            const int l = m & 2047;
            s4v v;
            #pragma unroll
            for (int r = 0; r < 4; ++r)
                v[r] = (short)f2bf(fmaf(CS1, (float)acc1[mi][nj][r],
                                   fmaf(CS2, (float)acc2[mi][nj][r], bs)));
            *(s4v*)(outb + (((size_t)((b << 10) + n)) << 11) + l) = v;
        }
    }
    #undef STAGE8
    #undef COMP8
}

// ---------------------------------------------------------------------------
// bf16 MFMA GEMM (V projection EPI=2; final projection EPI=1)
// ---------------------------------------------------------------------------
template<int EPI>
__global__ __launch_bounds__(256, 2) void gemm_mfma_bt(
    const u16* __restrict__ Ah, const u16* __restrict__ Bh,
    const float* __restrict__ bias, const float* __restrict__ resid,
    float* __restrict__ outp)
{
    __shared__ __align__(16) u16 lds[2 * 2 * 4096];
    const int t = threadIdx.x;
    const int w = t >> 6, lane = t & 63;
    const int2 tb = xcd_swizzle_8x128();
    const int m0 = tb.y * 128, n0 = tb.x * 128;
    const int srow = lane >> 2, sslot = lane & 3;
    const int r15 = lane & 15, kg = lane >> 4;
    const int wr = w >> 1, wc = w & 1;
    const int r4 = (lane >> 4) * 4;
    const int swz16 = (kg ^ (r15 & 3)) << 3;                 // u16 units
    const int a_off = ((wr * 64 + r15) << 5) + swz16;
    const int b_off = ((wc * 64 + r15) << 5) + swz16;

    f32x4 acc[4][4];
    #pragma unroll
    for (int i = 0; i < 4; ++i)
        #pragma unroll
        for (int j = 0; j < 4; ++j)
            acc[i][j] = (f32x4){0.f, 0.f, 0.f, 0.f};

    #define STAGE(buf, kt)                                                        \
    {                                                                             \
        const int k0s = (kt) * 32;                                                \
        u16* base = &lds[(buf) * 2 * 4096];                                       \
        _Pragma("unroll")                                                         \
        for (int i = 0; i < 2; ++i) {                                             \
            const int row = w * 32 + i * 16 + srow;                               \
            const int kch = ((sslot ^ (row & 3)) << 3);                           \
            const int loff = w * 1024 + i * 512;                                  \
            async16(&base[loff],        Ah + (size_t)(m0 + row) * 1024 + k0s + kch); \
            async16(&base[4096 + loff], Bh + (size_t)(n0 + row) * 1024 + k0s + kch); \
        }                                                                         \
    }

    #define COMPUTE(buf)                                                          \
    {                                                                             \
        const u16* cb = &lds[(buf) * 2 * 4096];                                   \
        short8 ah[4], bh[4];                                                      \
        _Pragma("unroll")                                                         \
        for (int mi = 0; mi < 4; ++mi) ah[mi] = *(const short8*)(cb + a_off + mi * 512); \
        _Pragma("unroll")                                                         \
        for (int nj = 0; nj < 4; ++nj) bh[nj] = *(const short8*)(cb + 4096 + b_off + nj * 512); \
        _Pragma("unroll")                                                         \
        for (int mi = 0; mi < 4; ++mi)                                            \
            _Pragma("unroll")                                                     \
            for (int nj = 0; nj < 4; ++nj)                                        \
                acc[mi][nj] = __builtin_amdgcn_mfma_f32_16x16x32_bf16(ah[mi], bh[nj], acc[mi][nj], 0, 0, 0); \
    }

    STAGE(0, 0);
    __syncthreads();
    int cur = 0;
    for (int kt = 0; kt < 31; ++kt) {
        STAGE(cur ^ 1, kt + 1);
        COMPUTE(cur);
        __syncthreads();
        cur ^= 1;
    }
    COMPUTE(cur);

    if (EPI == 2) {
        u16* outb = (u16*)outp;
        #pragma unroll
        for (int nj = 0; nj < 4; ++nj) {
            const int n = n0 + wc * 64 + nj * 16 + r15;
            const float bs = bias[n];
            #pragma unroll
            for (int mi = 0; mi < 4; ++mi) {
                const int m = m0 + wr * 64 + mi * 16 + r4;
                const int b = m >> 11;
                const int l = m & 2047;
                s4v v;
                #pragma unroll
                for (int r = 0; r < 4; ++r) v[r] = (short)f2bf(acc[mi][nj][r] + bs);
                *(s4v*)(outb + (((size_t)((b << 10) + n)) << 11) + l) = v;
            }
        }
    } else {
        #pragma unroll
        for (int mi = 0; mi < 4; ++mi) {
            #pragma unroll
            for (int r = 0; r < 4; ++r) {
                const int m = m0 + wr * 64 + mi * 16 + r4 + r;
                const float* rrow = resid + ((size_t)m << 10);
                float* orow = outp + ((size_t)m << 10);
                #pragma unroll
                for (int nj = 0; nj < 4; ++nj) {
                    const int n = n0 + wc * 64 + nj * 16 + r15;
                    orow[n] = acc[mi][nj][r] + bias[n] + rrow[n];
                }
            }
        }
    }
    #undef STAGE
    #undef COMPUTE
}

// ---------------------------------------------------------------------------
// Radix-8 Stockham FFT, N=2048, stages [8,8,8,4], 256 threads.
// ---------------------------------------------------------------------------
#define IDX(i) ((i) + ((i) >> 3))
#define FFT_BUF 2304

__device__ __forceinline__ float2 c_add(float2 a, float2 b){ return make_float2(a.x+b.x, a.y+b.y); }
__device__ __forceinline__ float2 c_sub(float2 a, float2 b){ return make_float2(a.x-b.x, a.y-b.y); }
__device__ __forceinline__ float2 cmul(float2 a, float2 b){
    return make_float2(fmaf(a.x, b.x, -a.y*b.y), fmaf(a.x, b.y, a.y*b.x));
}
template<bool INV>
__device__ __forceinline__ float2 rot90(float2 z) {
    return INV ? make_float2(-z.y, z.x) : make_float2(z.y, -z.x);
}

template<bool INV>
__device__ __forceinline__ void dft8(const float2* a, float2* y) {
    const float r = 0.70710678118654752f;
    float2 e0 = c_add(a[0], a[4]), e1 = c_sub(a[0], a[4]);
    float2 e2 = c_add(a[2], a[6]), e3 = rot90<INV>(c_sub(a[2], a[6]));
    float2 E0 = c_add(e0, e2), E2 = c_sub(e0, e2);
    float2 E1 = c_add(e1, e3), E3 = c_sub(e1, e3);
    float2 o0 = c_add(a[1], a[5]), o1 = c_sub(a[1], a[5]);
    float2 o2 = c_add(a[3], a[7]), o3 = rot90<INV>(c_sub(a[3], a[7]));
    float2 O0 = c_add(o0, o2), O2 = c_sub(o0, o2);
    float2 O1 = c_add(o1, o3), O3 = c_sub(o1, o3);
    float2 T1 = INV ? make_float2(r*(O1.x - O1.y), r*(O1.x + O1.y))
                    : make_float2(r*(O1.x + O1.y), r*(O1.y - O1.x));
    float2 T2 = rot90<INV>(O2);
    float2 T3 = INV ? make_float2(-r*(O3.x + O3.y), r*(O3.x - O3.y))
                    : make_float2(r*(O3.y - O3.x), -r*(O3.x + O3.y));
    y[0] = c_add(E0, O0); y[4] = c_sub(E0, O0);
    y[1] = c_add(E1, T1); y[5] = c_sub(E1, T1);
    y[2] = c_add(E2, T2); y[6] = c_sub(E2, T2);
    y[3] = c_add(E3, T3); y[7] = c_sub(E3, T3);
}

template<bool INV>
__device__ float2* fft2048_r8(float2* bufA, float2* bufB, const float2* twd, int tid)
{
    float2* src = bufA;
    float2* dst = bufB;
    #pragma unroll
    for (int st = 0; st < 3; ++st) {
        const int s = 1 << (3 * st);
        const int u = tid;
        const int sp = u & ~(s - 1);
        float2 a[8], y[8];
        #pragma unroll
        for (int t = 0; t < 8; ++t) a[t] = src[IDX(u + (t << 8))];
        dft8<INV>(a, y);
        float2 w1 = twd[sp];
        if (INV) w1.y = -w1.y;
        const int ob = u + 7 * sp;
        dst[IDX(ob)]     = y[0];
        dst[IDX(ob + s)] = cmul(y[1], w1);
        float2 w = w1;
        #pragma unroll
        for (int t = 2; t < 8; ++t) {
            w = cmul(w, w1);
            dst[IDX(ob + t * s)] = cmul(y[t], w);
        }
        __syncthreads();
        float2* tmp = src; src = dst; dst = tmp;
    }
    #pragma unroll
    for (int h = 0; h < 2; ++h) {
        const int u = tid + (h << 8);
        float2 a0 = src[IDX(u)],        a1 = src[IDX(u + 512)];
        float2 a2 = src[IDX(u + 1024)], a3 = src[IDX(u + 1536)];
        float2 b0 = c_add(a0, a2), b1 = c_sub(a0, a2);
        float2 b2 = c_add(a1, a3), b3 = rot90<INV>(c_sub(a1, a3));
        dst[IDX(u)]        = c_add(b0, b2);
        dst[IDX(u + 512)]  = c_add(b1, b3);
        dst[IDX(u + 1024)] = c_sub(b0, b2);
        dst[IDX(u + 1536)] = c_sub(b1, b3);
    }
    __syncthreads();
    return dst;
}

// ---------------------------------------------------------------------------
// F1: per (b,h,d-octet): FFT z=q+ik (bf16 inputs), accumulate S=Q*conj(K).
// ---------------------------------------------------------------------------
__global__ __launch_bounds__(256) void fft_corr_partial(
    const u16* __restrict__ qT, const u16* __restrict__ kT,
    float* __restrict__ part)
{
    __shared__ float2 bufA[FFT_BUF];
    __shared__ float2 bufB[FFT_BUF];
    __shared__ float2 twd[256];
    const int tid = threadIdx.x;
    const int blk = blockIdx.x;
    const int bh  = blk >> 3, g = blk & 7;
    {
        float s, c;
        sincosf((float)tid * 3.0679615757712823e-3f, &s, &c);
        twd[tid] = make_float2(c, -s);
    }
    float2 racc[4];
    #pragma unroll
    for (int ii = 0; ii < 4; ++ii) racc[ii] = make_float2(0.f, 0.f);
    float2 racc4 = make_float2(0.f, 0.f);

    const u16* qbase = qT + ((size_t)bh * DKK + g * 8) * LL;
    const u16* kbase = kT + ((size_t)bh * DKK + g * 8) * LL;
    for (int dd = 0; dd < 8; ++dd) {
        __syncthreads();
        const u16* qr = qbase + (size_t)dd * LL;
        const u16* kr = kbase + (size_t)dd * LL;
        short8 q8 = *(const short8*)(qr + tid * 8);
        short8 k8 = *(const short8*)(kr + tid * 8);
        #pragma unroll
        for (int j = 0; j < 8; ++j)
            bufA[IDX(tid * 8 + j)] = make_float2(bf2f((u16)q8[j]), bf2f((u16)k8[j]));
        __syncthreads();
        float2* res = fft2048_r8<false>(bufA, bufB, twd, tid);
        #pragma unroll
        for (int ii = 0; ii < 4; ++ii) {
            const int f = tid + (ii << 8);
            float2 zf = res[IDX(f)];
            float2 zc = res[IDX((2048 - f) & 2047)];
            float2 Q = make_float2(0.5f*(zf.x + zc.x), 0.5f*(zf.y - zc.y));
            float2 K = make_float2(0.5f*(zf.y + zc.y), -0.5f*(zf.x - zc.x));
            racc[ii].x += Q.x*K.x + Q.y*K.y;
            racc[ii].y += Q.y*K.x - Q.x*K.y;
        }
        if (tid == 0) {
            float2 zf = res[IDX(1024)];
            racc4.x += zf.x * zf.y;
        }
    }
    float* po = part + (size_t)blk * PART_STRIDE;
    #pragma unroll
    for (int ii = 0; ii < 4; ++ii) {
        const int f = tid + (ii << 8);
        po[2*f]     = racc[ii].x;
        po[2*f + 1] = racc[ii].y;
    }
    if (tid == 0) { po[2048] = racc4.x; po[2049] = racc4.y; }
}

// ---------------------------------------------------------------------------
// F2: per (b,h): sum 8 partials, Hermitian-extend, inverse FFT, top-7, softmax.
// ---------------------------------------------------------------------------
__global__ __launch_bounds__(256) void fft_inv_topk(
    const float* __restrict__ part, float* __restrict__ out1,
    float* __restrict__ topw, int* __restrict__ topi)
{
    __shared__ float2 bufA[FFT_BUF];
    __shared__ float2 bufB[FFT_BUF];
    __shared__ float2 twd[256];
    __shared__ float  mv[2048];
    __shared__ float  rv[256];
    __shared__ int    ri[256];
    __shared__ float  selv[TOPK];
    __shared__ int    seli[TOPK];
    const int tid = threadIdx.x;
    const int bh  = blockIdx.x;
    {
        float s, c;
        sincosf((float)tid * 3.0679615757712823e-3f, &s, &c);
        twd[tid] = make_float2(c, -s);
    }
    for (int f = tid; f < 1025; f += 256) {
        float sx = 0.f, sy = 0.f;
        for (int g2 = 0; g2 < 8; ++g2) {
            const float* po = part + (size_t)(bh * 8 + g2) * PART_STRIDE + 2*f;
            sx += po[0]; sy += po[1];
        }
        bufA[IDX(f)] = make_float2(sx, sy);
        if (f > 0 && f < 1024) bufA[IDX(2048 - f)] = make_float2(sx, -sy);
    }
    __syncthreads();
    float2* res = fft2048_r8<true>(bufA, bufB, twd, tid);
    const float scale = 1.0f / (2048.0f * 64.0f);
    #pragma unroll
    for (int j = 0; j < 8; ++j) {
        const int l = tid + (j << 8);
        mv[l] = res[IDX(l)].x * scale;
    }
    __syncthreads();
    for (int it = 0; it < TOPK; ++it) {
        float bvv = -3.0e38f; int bii = 0;
        #pragma unroll
        for (int c = 0; c < 8; ++c) {
            const int idx = tid * 8 + c;
            const float v = mv[idx];
            if (v > bvv) { bvv = v; bii = idx; }
        }
        rv[tid] = bvv; ri[tid] = bii;
        __syncthreads();
        for (int off = 128; off > 0; off >>= 1) {
            if (tid < off) {
                const float v2 = rv[tid + off]; const int i2 = ri[tid + off];
                if (v2 > rv[tid] || (v2 == rv[tid] && i2 < ri[tid])) {
                    rv[tid] = v2; ri[tid] = i2;
                }
            }
            __syncthreads();
        }
        if (tid == 0) { selv[it] = rv[0]; seli[it] = ri[0]; mv[ri[0]] = -3.0e38f; }
        __syncthreads();
    }
    if (tid == 0) {
        const float mx = selv[0];
        float e[TOPK]; float ssum = 0.f;
        #pragma unroll
        for (int i = 0; i < TOPK; ++i) { e[i] = expf(selv[i] - mx); ssum += e[i]; }
        const float inv = 1.0f / ssum;
        #pragma unroll
        for (int i = 0; i < TOPK; ++i) {
            const float w = e[i] * inv;
            out1[bh * TOPK + i] = w;
            topw[bh * TOPK + i] = w;
            topi[bh * TOPK + i] = seli[i];
        }
    }
}

// ---------------------------------------------------------------------------
// Fused gather + transpose: per (bh, d-half of 32): stage 32 v-rows in LDS,
// 7-tap circular gather, write agg ROW-MAJOR bf16 (B*L, D) directly.
// Dynamic LDS: 32*2048*2 = 131072 B.
// ---------------------------------------------------------------------------
__global__ __launch_bounds__(256) void gather_tr(
    const u16* __restrict__ vbf, const float* __restrict__ topw,
    const int* __restrict__ topi, u16* __restrict__ aggrow)
{
    extern __shared__ u16 vstage[];      // [32][2048]
    __shared__ float wv[TOPK];
    __shared__ int   wi[TOPK];
    const int blk  = blockIdx.x;         // bh*2 + half
    const int bh   = blk >> 1, half = blk & 1;
    const int b    = bh >> 4, h = bh & 15;
    const int tid  = threadIdx.x;
    if (tid < TOPK) {
        wv[tid] = topw[bh * TOPK + tid];
        wi[tid] = topi[bh * TOPK + tid];
    }
    const u16* vsrc = vbf + ((size_t)bh * DKK + half * 32) * LL;
    short8* vs8 = (short8*)vstage;
    #pragma unroll
    for (int k = 0; k < 32; ++k)
        vs8[tid + k * 256] = *(const short8*)(vsrc + (size_t)(tid + k * 256) * 8);
    __syncthreads();
    const int doff = h * 64 + half * 32;
    for (int c = 0; c < 8; ++c) {
        const int l = c * 256 + tid;
        u16* orow = aggrow + ((size_t)((b << 11) + l) << 10) + doff;
        short8 o[4];
        #pragma unroll
        for (int d = 0; d < 32; ++d) {
            float s = 0.f;
            #pragma unroll
            for (int i = 0; i < TOPK; ++i)
                s = fmaf(wv[i], bf2f(vstage[d * 2048 + ((l + wi[i]) & 2047)]), s);
            o[d >> 3][d & 7] = (short)f2bf(s);
        }
        #pragma unroll
        for (int q = 0; q < 4; ++q)
            *(short8*)(orow + q * 8) = o[q];
    }
}

// ---------------------------------------------------------------------------
extern "C" void kernel_launch(void* const* d_in, const int* in_sizes, int n_in,
                              void* d_out, int out_size, void* d_ws, size_t ws_size,
                              hipStream_t stream)
{
    const float* query = (const float*)d_in[0];
    const float* key   = (const float*)d_in[1];
    const float* value = (const float*)d_in[2];
    const float* Wq    = (const float*)d_in[3];
    const float* bq    = (const float*)d_in[4];
    const float* Wk    = (const float*)d_in[5];
    const float* bk    = (const float*)d_in[6];
    const float* Wv    = (const float*)d_in[7];
    const float* bv    = (const float*)d_in[8];
    const float* Wo    = (const float*)d_in[9];
    const float* bo    = (const float*)d_in[10];
    float* out = (float*)d_out;
    char*  ws  = (char*)d_ws;

    char* qxh = (char*)(ws + QXH_B);
    char* qxl = (char*)(ws + QXL_B);
    char* kxh = (char*)(ws + KXH_B);
    char* kxl = (char*)(ws + KXL_B);
    u16*  vxh = (u16*)(ws + VXH_B);
    char* qwh = (char*)(ws + QWH_B);
    char* qwl = (char*)(ws + QWL_B);
    char* kwh = (char*)(ws + KWH_B);
    char* kwl = (char*)(ws + KWL_B);
    u16*  vwh = (u16*)(ws + VWH_B);
    u16*  owh = (u16*)(ws + OWH_B);
    u16*  qTb = (u16*)(ws + QTB_B);
    u16*  kTb = (u16*)(ws + KTB_B);
    u16*  vbf = (u16*)(ws + VBF_B);
    float* part = (float*)(ws + PART_B);
    float* topw = (float*)(ws + TOPW_B);
    int*   topi = (int*)(ws + TOPI_B);
    u16*  aggrow = (u16*)(ws + QTB_B);   // reuse qTb after F1

    dim3 gg(DD / 128, (BB * LL) / 128);   // (8, 128)

    // all conversions, one launch, 4 elems/thread, fully coalesced
    k_conv_all<<<53248, 256, 0, stream>>>(query, key, value, Wq, Wk, Wv, Wo,
                                          qxh, qxl, kxh, kxl, vxh,
                                          qwh, qwl, kwh, kwl, vwh, owh);
    // projections
    gemm_i8split<<<gg, 256, 0, stream>>>(qxh, qxl, qwh, qwl, bq, qTb);
    gemm_i8split<<<gg, 256, 0, stream>>>(kxh, kxl, kwh, kwl, bk, kTb);
    gemm_mfma_bt<2><<<gg, 256, 0, stream>>>(vxh, vwh, bv, nullptr, (float*)vbf);
    // autocorrelation
    fft_corr_partial<<<BB * HH * 8, 256, 0, stream>>>(qTb, kTb, part);
    fft_inv_topk<<<BB * HH, 256, 0, stream>>>(part, out + 16777216, topw, topi);
    gather_tr<<<BB * HH * 2, 256, 131072, stream>>>(vbf, topw, topi, aggrow);
    // output projection + residual
    gemm_mfma_bt<1><<<gg, 256, 0, stream>>>(aggrow, owh, bo, query, out);
}

// Round 12
// 363.655 us; speedup vs baseline: 1.0624x; 1.0624x over previous
//
#include <hip/hip_runtime.h>
#include <hip/hip_bf16.h>
#include <math.h>

#define BB   8
#define LL   2048
#define DD   1024
#define HH   16
#define DKK  64
#define TOPK 7

typedef unsigned short u16;
typedef short short8 __attribute__((ext_vector_type(8)));
typedef short s4v    __attribute__((ext_vector_type(4)));
typedef float f32x4  __attribute__((ext_vector_type(4)));
typedef int   int4v  __attribute__((ext_vector_type(4)));

// ---- workspace layout (BYTE offsets), high-water = 209,715,200 B ----
#define QXH_B   0ull            // 16MB i8 q-hi   | later: PART (8.45MB)
#define QXL_B   16777216ull     // 16MB i8 q-lo   | later: TOPW/TOPI
#define KXH_B   33554432ull     // 16MB i8 k-hi
#define KXL_B   50331648ull     // 16MB i8 k-lo
#define VXH_B   67108864ull     // 32MB bf16 value
#define QWH_B   100663296ull    // 1MB
#define QWL_B   101711872ull    // 1MB
#define KWH_B   102760448ull    // 1MB
#define KWL_B   103809024ull    // 1MB
#define VWH_B   104857600ull    // 2MB
#define OWH_B   106954752ull    // 2MB
#define QTB_B   109051904ull    // 32MB bf16 qT (B,D,L) | later: aggrow
#define KTB_B   142606336ull    // 32MB bf16 kT
#define VBF_B   176160768ull    // 32MB bf16 v (B,D,L); ends 209,715,200
#define PART_B  0ull
#define PART_STRIDE 2064
#define TOPW_B  16777216ull
#define TOPI_B  16780800ull

// fixed-point scales: x on +-6 (16-bit), W on +-0.1875 (16-bit)
#define SX_INV  5461.3333f
#define SW_INV  174762.67f
#define CS1     6.8664551e-5f   // 65536 * sx * sw
#define CS2     2.6822090e-7f   // 256 * sx * sw

// XCD-aware bijective block swizzle (1024 blocks).
__device__ __forceinline__ int2 xcd_swizzle_8x128() {
    const int lin = blockIdx.y * gridDim.x + blockIdx.x;   // [0,1024)
    const int swz = (lin & 7) * 128 + (lin >> 3);
    return make_int2(swz & 7, swz >> 3);                   // (n-tile, m-tile)
}

// ---------------------------------------------------------------------------
// helpers
// ---------------------------------------------------------------------------
__device__ __forceinline__ u16 f2bf(float f) {
    unsigned u = __float_as_uint(f);
    unsigned r = u + 0x7FFFu + ((u >> 16) & 1u);
    return (u16)(r >> 16);
}
__device__ __forceinline__ float bf2f(u16 h) {
    return __uint_as_float((unsigned)h << 16);
}

__device__ __forceinline__ void split4_i8(const float* __restrict__ x,
                                          char* __restrict__ hi,
                                          char* __restrict__ lo,
                                          float inv_s, size_t i) {
    float4 t = ((const float4*)x)[i];
    float f[4] = {t.x, t.y, t.z, t.w};
    unsigned hp = 0, lp = 0;
    #pragma unroll
    for (int j = 0; j < 4; ++j) {
        int q = __float2int_rn(f[j] * inv_s);
        q = min(max(q, -32639), 32639);
        int xl = ((q + 128) & 255) - 128;
        int xh = (q - xl) >> 8;
        hp |= ((unsigned)(xh & 255)) << (8 * j);
        lp |= ((unsigned)(xl & 255)) << (8 * j);
    }
    ((unsigned*)hi)[i] = hp;
    ((unsigned*)lo)[i] = lp;
}

__device__ __forceinline__ void cvt4_bf(const float* __restrict__ x,
                                        u16* __restrict__ o, size_t i) {
    float4 t = ((const float4*)x)[i];
    s4v h;
    h[0] = (short)f2bf(t.x); h[1] = (short)f2bf(t.y);
    h[2] = (short)f2bf(t.z); h[3] = (short)f2bf(t.w);
    *(s4v*)(o + i * 4) = h;
}

// ---------------------------------------------------------------------------
// ALL conversions, one launch, 4 elems/thread, fully coalesced.
// ---------------------------------------------------------------------------
__global__ __launch_bounds__(256) void k_conv_all(
    const float* __restrict__ q, const float* __restrict__ k,
    const float* __restrict__ v,
    const float* __restrict__ Wq, const float* __restrict__ Wk,
    const float* __restrict__ Wv, const float* __restrict__ Wo,
    char* __restrict__ qh, char* __restrict__ ql,
    char* __restrict__ kh, char* __restrict__ kl, u16* __restrict__ vx,
    char* __restrict__ qwh, char* __restrict__ qwl,
    char* __restrict__ kwh, char* __restrict__ kwl,
    u16* __restrict__ vwh, u16* __restrict__ owh)
{
    const int b = blockIdx.x;
    const int t = threadIdx.x;
    if (b < 16384) {
        split4_i8(q, qh, ql, SX_INV, (size_t)b * 256 + t);
    } else if (b < 32768) {
        split4_i8(k, kh, kl, SX_INV, (size_t)(b - 16384) * 256 + t);
    } else if (b < 49152) {
        cvt4_bf(v, vx, (size_t)(b - 32768) * 256 + t);
    } else if (b < 50176) {
        split4_i8(Wq, qwh, qwl, SW_INV, (size_t)(b - 49152) * 256 + t);
    } else if (b < 51200) {
        split4_i8(Wk, kwh, kwl, SW_INV, (size_t)(b - 50176) * 256 + t);
    } else if (b < 52224) {
        cvt4_bf(Wv, vwh, (size_t)(b - 51200) * 256 + t);
    } else {
        cvt4_bf(Wo, owh, (size_t)(b - 52224) * 256 + t);
    }
}

// ---------------------------------------------------------------------------
// async global->LDS (16B, wave-uniform LDS base + lane*16)
// ---------------------------------------------------------------------------
__device__ __forceinline__ void async16(u16* l, const u16* g) {
    __builtin_amdgcn_global_load_lds(
        (const __attribute__((address_space(1))) void*)g,
        (__attribute__((address_space(3))) void*)l, 16, 0, 0);
}
__device__ __forceinline__ void async16b(char* l, const char* g) {
    __builtin_amdgcn_global_load_lds(
        (const __attribute__((address_space(1))) void*)g,
        (__attribute__((address_space(3))) void*)l, 16, 0, 0);
}

// ---------------------------------------------------------------------------
// i8-split MFMA GEMM (Q/K projections) — unchanged (128² 2-phase)
// ---------------------------------------------------------------------------
__global__ __launch_bounds__(256, 2) void gemm_i8split(
    const char* __restrict__ Ah, const char* __restrict__ Al,
    const char* __restrict__ Bh, const char* __restrict__ Bl,
    const float* __restrict__ bias, u16* __restrict__ outb)
{
    __shared__ __align__(16) char lds[2][4][8192];
    const int t = threadIdx.x;
    const int w = t >> 6, lane = t & 63;
    const int2 tb = xcd_swizzle_8x128();
    const int m0 = tb.y * 128, n0 = tb.x * 128;
    const int srow = lane >> 2, sslot = lane & 3;
    const int r15 = lane & 15, kg = lane >> 4;
    const int wr = w >> 1, wc = w & 1;
    const int r4 = (lane >> 4) * 4;
    const int swzb = (kg ^ (r15 & 3)) << 4;
    const int a_off = (wr * 64 + r15) * 64 + swzb;
    const int b_off = (wc * 64 + r15) * 64 + swzb;

    int4v acc1[4][4], acc2[4][4];
    #pragma unroll
    for (int i = 0; i < 4; ++i)
        #pragma unroll
        for (int j = 0; j < 4; ++j) {
            acc1[i][j] = (int4v){0,0,0,0};
            acc2[i][j] = (int4v){0,0,0,0};
        }

    #define STAGE8(buf, kt)                                                       \
    {                                                                             \
        const int gc0 = (kt) * 64;                                                \
        _Pragma("unroll")                                                         \
        for (int i = 0; i < 2; ++i) {                                             \
            const int row  = w * 32 + i * 16 + srow;                              \
            const int kch  = (sslot ^ (row & 3)) << 4;                            \
            const int loff = w * 2048 + i * 1024;                                 \
            async16b(&lds[buf][0][loff], Ah + (size_t)(m0 + row) * 1024 + gc0 + kch); \
            async16b(&lds[buf][1][loff], Bh + (size_t)(n0 + row) * 1024 + gc0 + kch); \
            async16b(&lds[buf][2][loff], Al + (size_t)(m0 + row) * 1024 + gc0 + kch); \
            async16b(&lds[buf][3][loff], Bl + (size_t)(n0 + row) * 1024 + gc0 + kch); \
        }                                                                         \
    }

    #define COMP8(buf)                                                            \
    {                                                                             \
        const char* cb = &lds[buf][0][0];                                         \
        int4v ah[4], bh4[4], al[4], bl[4];                                        \
        _Pragma("unroll")                                                         \
        for (int mi = 0; mi < 4; ++mi) ah[mi] = *(const int4v*)(cb + a_off + mi * 1024); \
        _Pragma("unroll")                                                         \
        for (int nj = 0; nj < 4; ++nj) bh4[nj] = *(const int4v*)(cb + 8192 + b_off + nj * 1024); \
        _Pragma("unroll")                                                         \
        for (int mi = 0; mi < 4; ++mi)                                            \
            _Pragma("unroll")                                                     \
            for (int nj = 0; nj < 4; ++nj)                                        \
                acc1[mi][nj] = __builtin_amdgcn_mfma_i32_16x16x64_i8(ah[mi], bh4[nj], acc1[mi][nj], 0, 0, 0); \
        _Pragma("unroll")                                                         \
        for (int nj = 0; nj < 4; ++nj) bl[nj] = *(const int4v*)(cb + 24576 + b_off + nj * 1024); \
        _Pragma("unroll")                                                         \
        for (int mi = 0; mi < 4; ++mi)                                            \
            _Pragma("unroll")                                                     \
            for (int nj = 0; nj < 4; ++nj)                                        \
                acc2[mi][nj] = __builtin_amdgcn_mfma_i32_16x16x64_i8(ah[mi], bl[nj], acc2[mi][nj], 0, 0, 0); \
        _Pragma("unroll")                                                         \
        for (int mi = 0; mi < 4; ++mi) al[mi] = *(const int4v*)(cb + 16384 + a_off + mi * 1024); \
        _Pragma("unroll")                                                         \
        for (int mi = 0; mi < 4; ++mi)                                            \
            _Pragma("unroll")                                                     \
            for (int nj = 0; nj < 4; ++nj)                                        \
                acc2[mi][nj] = __builtin_amdgcn_mfma_i32_16x16x64_i8(al[mi], bh4[nj], acc2[mi][nj], 0, 0, 0); \
    }

    STAGE8(0, 0);
    __syncthreads();
    int cur = 0;
    for (int kt = 0; kt < 15; ++kt) {
        STAGE8(cur ^ 1, kt + 1);
        COMP8(cur);
        __syncthreads();
        cur ^= 1;
    }
    COMP8(cur);

    #pragma unroll
    for (int nj = 0; nj < 4; ++nj) {
        const int n = n0 + wc * 64 + nj * 16 + r15;
        const float bs = bias[n];
        #pragma unroll
        for (int mi = 0; mi < 4; ++mi) {
            const int m = m0 + wr * 64 + mi * 16 + r4;
            const int b = m >> 11;
            const int l = m & 2047;
            s4v v;
            #pragma unroll
            for (int r = 0; r < 4; ++r)
                v[r] = (short)f2bf(fmaf(CS1, (float)acc1[mi][nj][r],
                                   fmaf(CS2, (float)acc2[mi][nj][r], bs)));
            *(s4v*)(outb + (((size_t)((b << 10) + n)) << 11) + l) = v;
        }
    }
    #undef STAGE8
    #undef COMP8
}

// ---------------------------------------------------------------------------
// NEW: 256x256 phase-pipelined bf16 GEMM (8 waves, BK=64, 2-dbuf 128KB LDS,
// per-phase {ds_read || stage-issue || MFMA}, counted drain once per K-tile).
// EPI=1: f32 row-major + bias + resid; EPI=2: bf16 transposed (B,N,L) + bias.
// ---------------------------------------------------------------------------
template<int EPI>
__global__ __launch_bounds__(512, 2) void gemm_bf16_256(
    const u16* __restrict__ A, const u16* __restrict__ B,
    const float* __restrict__ bias, const float* __restrict__ resid,
    float* __restrict__ outp)
{
    extern __shared__ u16 ldsx[];          // lsA[2][16384] | lsB[2][16384]
    u16* lsA = ldsx;
    u16* lsB = ldsx + 32768;
    const int t = threadIdx.x;
    const int wid = t >> 6, lane = t & 63;
    const int wr = wid >> 2, wc = wid & 3;          // 2 x 4 waves
    const int r15 = lane & 15, kg = lane >> 4, r4 = kg * 4;
    // 256 blocks, bijective XCD swizzle (256 % 8 == 0)
    const int lin = blockIdx.y * gridDim.x + blockIdx.x;
    const int swz = (lin & 7) * 32 + (lin >> 3);
    const int n0 = (swz & 3) * 256, m0 = (swz >> 2) * 256;
    // staging: chunk = 128 rows x 64 k of one matrix (16KB); 2 loads/thread
    const int sb = wid * 2;                // sub-block base (x8 rows per 1KB)
    const int sr = lane >> 3;              // row within 8
    const int ss = lane & 7;               // 16B slot in 128B row

    // stage one chunk: rows rb..rb+127 of ktile kt -> buffer bufb of ls
    #define STG(bufb, ls, rb, src, base0, kt)                                   \
    {                                                                           \
        _Pragma("unroll")                                                       \
        for (int j = 0; j < 2; ++j) {                                           \
            const int r = (rb) + (sb + j) * 8 + sr;                             \
            async16(ls + (size_t)(bufb) * 16384 + (size_t)(rb) * 64 + (size_t)(sb + j) * 512, \
                    src + (size_t)((base0) + r) * 1024 + (kt) * 64 + ((ss ^ (r & 7)) << 3)); \
        }                                                                       \
    }

    f32x4 acc[8][4];
    #pragma unroll
    for (int i = 0; i < 8; ++i)
        #pragma unroll
        for (int j = 0; j < 4; ++j)
            acc[i][j] = (f32x4){0.f, 0.f, 0.f, 0.f};

    // prologue: stage all 4 chunks of K-tile 0 into buffer 0
    STG(0, lsB, 0,   B, n0, 0);
    STG(0, lsB, 128, B, n0, 0);
    STG(0, lsA, 0,   A, m0, 0);
    STG(0, lsA, 128, A, m0, 0);

    for (int kt = 0; kt < 16; ++kt) {
        const int bf = kt & 1, nb = bf ^ 1;
        // tile entry: this wave's loads for tile kt landed; all waves agree
        asm volatile("s_waitcnt vmcnt(0)" ::: "memory");
        asm volatile("s_barrier" ::: "memory");
        // B band for this wave (8 ds_read_b128), held across phases
        short8 bfr[4][2];
        #pragma unroll
        for (int nj = 0; nj < 4; ++nj)
            #pragma unroll
            for (int ks = 0; ks < 2; ++ks) {
                const int row = wc * 64 + nj * 16 + r15;
                bfr[nj][ks] = *(const short8*)(lsB + (size_t)bf * 16384 +
                    (size_t)row * 64 + ((((ks << 2) + kg) ^ (row & 7)) << 3));
            }
        #pragma unroll
        for (int p = 0; p < 4; ++p) {
            short8 afr[2][2];
            #pragma unroll
            for (int mh = 0; mh < 2; ++mh)
                #pragma unroll
                for (int ks = 0; ks < 2; ++ks) {
                    const int row = wr * 128 + (p * 2 + mh) * 16 + r15;
                    afr[mh][ks] = *(const short8*)(lsA + (size_t)bf * 16384 +
                        (size_t)row * 64 + ((((ks << 2) + kg) ^ (row & 7)) << 3));
                }
            if (kt < 15) {
                if (p == 0)      { STG(nb, lsB, 0,   B, n0, kt + 1); }
                else if (p == 1) { STG(nb, lsB, 128, B, n0, kt + 1); }
                else if (p == 2) { STG(nb, lsA, 0,   A, m0, kt + 1); }
                else             { STG(nb, lsA, 128, A, m0, kt + 1); }
            }
            asm volatile("s_barrier" ::: "memory");
            __builtin_amdgcn_s_setprio(1);
            #pragma unroll
            for (int mh = 0; mh < 2; ++mh)
                #pragma unroll
                for (int nj = 0; nj < 4; ++nj)
                    #pragma unroll
                    for (int ks = 0; ks < 2; ++ks)
                        acc[p * 2 + mh][nj] = __builtin_amdgcn_mfma_f32_16x16x32_bf16(
                            afr[mh][ks], bfr[nj][ks], acc[p * 2 + mh][nj], 0, 0, 0);
            __builtin_amdgcn_s_setprio(0);
            asm volatile("s_barrier" ::: "memory");
        }
    }

    if (EPI == 2) {
        u16* outb = (u16*)outp;
        #pragma unroll
        for (int nj = 0; nj < 4; ++nj) {
            const int n = n0 + wc * 64 + nj * 16 + r15;
            const float bs = bias[n];
            #pragma unroll
            for (int mi = 0; mi < 8; ++mi) {
                const int m = m0 + wr * 128 + mi * 16 + r4;
                const int b = m >> 11;
                const int l = m & 2047;
                s4v v;
                #pragma unroll
                for (int r = 0; r < 4; ++r) v[r] = (short)f2bf(acc[mi][nj][r] + bs);
                *(s4v*)(outb + (((size_t)((b << 10) + n)) << 11) + l) = v;
            }
        }
    } else {
        #pragma unroll
        for (int mi = 0; mi < 8; ++mi) {
            #pragma unroll
            for (int r = 0; r < 4; ++r) {
                const int m = m0 + wr * 128 + mi * 16 + r4 + r;
                const float* rrow = resid + ((size_t)m << 10);
                float* orow = outp + ((size_t)m << 10);
                #pragma unroll
                for (int nj = 0; nj < 4; ++nj) {
                    const int n = n0 + wc * 64 + nj * 16 + r15;
                    orow[n] = acc[mi][nj][r] + bias[n] + rrow[n];
                }
            }
        }
    }
    #undef STG
}

// ---------------------------------------------------------------------------
// Radix-8 Stockham FFT, N=2048, stages [8,8,8,4], 256 threads.
// ---------------------------------------------------------------------------
#define IDX(i) ((i) + ((i) >> 3))
#define FFT_BUF 2304

__device__ __forceinline__ float2 c_add(float2 a, float2 b){ return make_float2(a.x+b.x, a.y+b.y); }
__device__ __forceinline__ float2 c_sub(float2 a, float2 b){ return make_float2(a.x-b.x, a.y-b.y); }
__device__ __forceinline__ float2 cmul(float2 a, float2 b){
    return make_float2(fmaf(a.x, b.x, -a.y*b.y), fmaf(a.x, b.y, a.y*b.x));
}
template<bool INV>
__device__ __forceinline__ float2 rot90(float2 z) {
    return INV ? make_float2(-z.y, z.x) : make_float2(z.y, -z.x);
}

template<bool INV>
__device__ __forceinline__ void dft8(const float2* a, float2* y) {
    const float r = 0.70710678118654752f;
    float2 e0 = c_add(a[0], a[4]), e1 = c_sub(a[0], a[4]);
    float2 e2 = c_add(a[2], a[6]), e3 = rot90<INV>(c_sub(a[2], a[6]));
    float2 E0 = c_add(e0, e2), E2 = c_sub(e0, e2);
    float2 E1 = c_add(e1, e3), E3 = c_sub(e1, e3);
    float2 o0 = c_add(a[1], a[5]), o1 = c_sub(a[1], a[5]);
    float2 o2 = c_add(a[3], a[7]), o3 = rot90<INV>(c_sub(a[3], a[7]));
    float2 O0 = c_add(o0, o2), O2 = c_sub(o0, o2);
    float2 O1 = c_add(o1, o3), O3 = c_sub(o1, o3);
    float2 T1 = INV ? make_float2(r*(O1.x - O1.y), r*(O1.x + O1.y))
                    : make_float2(r*(O1.x + O1.y), r*(O1.y - O1.x));
    float2 T2 = rot90<INV>(O2);
    float2 T3 = INV ? make_float2(-r*(O3.x + O3.y), r*(O3.x - O3.y))
                    : make_float2(r*(O3.y - O3.x), -r*(O3.x + O3.y));
    y[0] = c_add(E0, O0); y[4] = c_sub(E0, O0);
    y[1] = c_add(E1, T1); y[5] = c_sub(E1, T1);
    y[2] = c_add(E2, T2); y[6] = c_sub(E2, T2);
    y[3] = c_add(E3, T3); y[7] = c_sub(E3, T3);
}

template<bool INV>
__device__ float2* fft2048_r8(float2* bufA, float2* bufB, const float2* twd, int tid)
{
    float2* src = bufA;
    float2* dst = bufB;
    #pragma unroll
    for (int st = 0; st < 3; ++st) {
        const int s = 1 << (3 * st);
        const int u = tid;
        const int sp = u & ~(s - 1);
        float2 a[8], y[8];
        #pragma unroll
        for (int t = 0; t < 8; ++t) a[t] = src[IDX(u + (t << 8))];
        dft8<INV>(a, y);
        float2 w1 = twd[sp];
        if (INV) w1.y = -w1.y;
        const int ob = u + 7 * sp;
        dst[IDX(ob)]     = y[0];
        dst[IDX(ob + s)] = cmul(y[1], w1);
        float2 w = w1;
        #pragma unroll
        for (int t = 2; t < 8; ++t) {
            w = cmul(w, w1);
            dst[IDX(ob + t * s)] = cmul(y[t], w);
        }
        __syncthreads();
        float2* tmp = src; src = dst; dst = tmp;
    }
    #pragma unroll
    for (int h = 0; h < 2; ++h) {
        const int u = tid + (h << 8);
        float2 a0 = src[IDX(u)],        a1 = src[IDX(u + 512)];
        float2 a2 = src[IDX(u + 1024)], a3 = src[IDX(u + 1536)];
        float2 b0 = c_add(a0, a2), b1 = c_sub(a0, a2);
        float2 b2 = c_add(a1, a3), b3 = rot90<INV>(c_sub(a1, a3));
        dst[IDX(u)]        = c_add(b0, b2);
        dst[IDX(u + 512)]  = c_add(b1, b3);
        dst[IDX(u + 1024)] = c_sub(b0, b2);
        dst[IDX(u + 1536)] = c_sub(b1, b3);
    }
    __syncthreads();
    return dst;
}

// ---------------------------------------------------------------------------
// F1: per (b,h,d-octet): FFT z=q+ik (bf16 inputs), accumulate S=Q*conj(K).
// ---------------------------------------------------------------------------
__global__ __launch_bounds__(256) void fft_corr_partial(
    const u16* __restrict__ qT, const u16* __restrict__ kT,
    float* __restrict__ part)
{
    __shared__ float2 bufA[FFT_BUF];
    __shared__ float2 bufB[FFT_BUF];
    __shared__ float2 twd[256];
    const int tid = threadIdx.x;
    const int blk = blockIdx.x;
    const int bh  = blk >> 3, g = blk & 7;
    {
        float s, c;
        sincosf((float)tid * 3.0679615757712823e-3f, &s, &c);
        twd[tid] = make_float2(c, -s);
    }
    float2 racc[4];
    #pragma unroll
    for (int ii = 0; ii < 4; ++ii) racc[ii] = make_float2(0.f, 0.f);
    float2 racc4 = make_float2(0.f, 0.f);

    const u16* qbase = qT + ((size_t)bh * DKK + g * 8) * LL;
    const u16* kbase = kT + ((size_t)bh * DKK + g * 8) * LL;
    for (int dd = 0; dd < 8; ++dd) {
        __syncthreads();
        const u16* qr = qbase + (size_t)dd * LL;
        const u16* kr = kbase + (size_t)dd * LL;
        short8 q8 = *(const short8*)(qr + tid * 8);
        short8 k8 = *(const short8*)(kr + tid * 8);
        #pragma unroll
        for (int j = 0; j < 8; ++j)
            bufA[IDX(tid * 8 + j)] = make_float2(bf2f((u16)q8[j]), bf2f((u16)k8[j]));
        __syncthreads();
        float2* res = fft2048_r8<false>(bufA, bufB, twd, tid);
        #pragma unroll
        for (int ii = 0; ii < 4; ++ii) {
            const int f = tid + (ii << 8);
            float2 zf = res[IDX(f)];
            float2 zc = res[IDX((2048 - f) & 2047)];
            float2 Q = make_float2(0.5f*(zf.x + zc.x), 0.5f*(zf.y - zc.y));
            float2 K = make_float2(0.5f*(zf.y + zc.y), -0.5f*(zf.x - zc.x));
            racc[ii].x += Q.x*K.x + Q.y*K.y;
            racc[ii].y += Q.y*K.x - Q.x*K.y;
        }
        if (tid == 0) {
            float2 zf = res[IDX(1024)];
            racc4.x += zf.x * zf.y;
        }
    }
    float* po = part + (size_t)blk * PART_STRIDE;
    #pragma unroll
    for (int ii = 0; ii < 4; ++ii) {
        const int f = tid + (ii << 8);
        po[2*f]     = racc[ii].x;
        po[2*f + 1] = racc[ii].y;
    }
    if (tid == 0) { po[2048] = racc4.x; po[2049] = racc4.y; }
}

// ---------------------------------------------------------------------------
// F2: per (b,h): sum 8 partials, Hermitian-extend, inverse FFT, top-7, softmax.
// ---------------------------------------------------------------------------
__global__ __launch_bounds__(256) void fft_inv_topk(
    const float* __restrict__ part, float* __restrict__ out1,
    float* __restrict__ topw, int* __restrict__ topi)
{
    __shared__ float2 bufA[FFT_BUF];
    __shared__ float2 bufB[FFT_BUF];
    __shared__ float2 twd[256];
    __shared__ float  mv[2048];
    __shared__ float  rv[256];
    __shared__ int    ri[256];
    __shared__ float  selv[TOPK];
    __shared__ int    seli[TOPK];
    const int tid = threadIdx.x;
    const int bh  = blockIdx.x;
    {
        float s, c;
        sincosf((float)tid * 3.0679615757712823e-3f, &s, &c);
        twd[tid] = make_float2(c, -s);
    }
    for (int f = tid; f < 1025; f += 256) {
        float sx = 0.f, sy = 0.f;
        for (int g2 = 0; g2 < 8; ++g2) {
            const float* po = part + (size_t)(bh * 8 + g2) * PART_STRIDE + 2*f;
            sx += po[0]; sy += po[1];
        }
        bufA[IDX(f)] = make_float2(sx, sy);
        if (f > 0 && f < 1024) bufA[IDX(2048 - f)] = make_float2(sx, -sy);
    }
    __syncthreads();
    float2* res = fft2048_r8<true>(bufA, bufB, twd, tid);
    const float scale = 1.0f / (2048.0f * 64.0f);
    #pragma unroll
    for (int j = 0; j < 8; ++j) {
        const int l = tid + (j << 8);
        mv[l] = res[IDX(l)].x * scale;
    }
    __syncthreads();
    for (int it = 0; it < TOPK; ++it) {
        float bvv = -3.0e38f; int bii = 0;
        #pragma unroll
        for (int c = 0; c < 8; ++c) {
            const int idx = tid * 8 + c;
            const float v = mv[idx];
            if (v > bvv) { bvv = v; bii = idx; }
        }
        rv[tid] = bvv; ri[tid] = bii;
        __syncthreads();
        for (int off = 128; off > 0; off >>= 1) {
            if (tid < off) {
                const float v2 = rv[tid + off]; const int i2 = ri[tid + off];
                if (v2 > rv[tid] || (v2 == rv[tid] && i2 < ri[tid])) {
                    rv[tid] = v2; ri[tid] = i2;
                }
            }
            __syncthreads();
        }
        if (tid == 0) { selv[it] = rv[0]; seli[it] = ri[0]; mv[ri[0]] = -3.0e38f; }
        __syncthreads();
    }
    if (tid == 0) {
        const float mx = selv[0];
        float e[TOPK]; float ssum = 0.f;
        #pragma unroll
        for (int i = 0; i < TOPK; ++i) { e[i] = expf(selv[i] - mx); ssum += e[i]; }
        const float inv = 1.0f / ssum;
        #pragma unroll
        for (int i = 0; i < TOPK; ++i) {
            const float w = e[i] * inv;
            out1[bh * TOPK + i] = w;
            topw[bh * TOPK + i] = w;
            topi[bh * TOPK + i] = seli[i];
        }
    }
}

// ---------------------------------------------------------------------------
// Fused gather + transpose (dynamic LDS 131072 B)
// ---------------------------------------------------------------------------
__global__ __launch_bounds__(256) void gather_tr(
    const u16* __restrict__ vbf, const float* __restrict__ topw,
    const int* __restrict__ topi, u16* __restrict__ aggrow)
{
    extern __shared__ u16 vstage[];      // [32][2048]
    __shared__ float wv[TOPK];
    __shared__ int   wi[TOPK];
    const int blk  = blockIdx.x;         // bh*2 + half
    const int bh   = blk >> 1, half = blk & 1;
    const int b    = bh >> 4, h = bh & 15;
    const int tid  = threadIdx.x;
    if (tid < TOPK) {
        wv[tid] = topw[bh * TOPK + tid];
        wi[tid] = topi[bh * TOPK + tid];
    }
    const u16* vsrc = vbf + ((size_t)bh * DKK + half * 32) * LL;
    short8* vs8 = (short8*)vstage;
    #pragma unroll
    for (int k = 0; k < 32; ++k)
        vs8[tid + k * 256] = *(const short8*)(vsrc + (size_t)(tid + k * 256) * 8);
    __syncthreads();
    const int doff = h * 64 + half * 32;
    for (int c = 0; c < 8; ++c) {
        const int l = c * 256 + tid;
        u16* orow = aggrow + ((size_t)((b << 11) + l) << 10) + doff;
        short8 o[4];
        #pragma unroll
        for (int d = 0; d < 32; ++d) {
            float s = 0.f;
            #pragma unroll
            for (int i = 0; i < TOPK; ++i)
                s = fmaf(wv[i], bf2f(vstage[d * 2048 + ((l + wi[i]) & 2047)]), s);
            o[d >> 3][d & 7] = (short)f2bf(s);
        }
        #pragma unroll
        for (int q = 0; q < 4; ++q)
            *(short8*)(orow + q * 8) = o[q];
    }
}

// ---------------------------------------------------------------------------
extern "C" void kernel_launch(void* const* d_in, const int* in_sizes, int n_in,
                              void* d_out, int out_size, void* d_ws, size_t ws_size,
                              hipStream_t stream)
{
    const float* query = (const float*)d_in[0];
    const float* key   = (const float*)d_in[1];
    const float* value = (const float*)d_in[2];
    const float* Wq    = (const float*)d_in[3];
    const float* bq    = (const float*)d_in[4];
    const float* Wk    = (const float*)d_in[5];
    const float* bk    = (const float*)d_in[6];
    const float* Wv    = (const float*)d_in[7];
    const float* bv    = (const float*)d_in[8];
    const float* Wo    = (const float*)d_in[9];
    const float* bo    = (const float*)d_in[10];
    float* out = (float*)d_out;
    char*  ws  = (char*)d_ws;

    char* qxh = (char*)(ws + QXH_B);
    char* qxl = (char*)(ws + QXL_B);
    char* kxh = (char*)(ws + KXH_B);
    char* kxl = (char*)(ws + KXL_B);
    u16*  vxh = (u16*)(ws + VXH_B);
    char* qwh = (char*)(ws + QWH_B);
    char* qwl = (char*)(ws + QWL_B);
    char* kwh = (char*)(ws + KWH_B);
    char* kwl = (char*)(ws + KWL_B);
    u16*  vwh = (u16*)(ws + VWH_B);
    u16*  owh = (u16*)(ws + OWH_B);
    u16*  qTb = (u16*)(ws + QTB_B);
    u16*  kTb = (u16*)(ws + KTB_B);
    u16*  vbf = (u16*)(ws + VBF_B);
    float* part = (float*)(ws + PART_B);
    float* topw = (float*)(ws + TOPW_B);
    int*   topi = (int*)(ws + TOPI_B);
    u16*  aggrow = (u16*)(ws + QTB_B);   // reuse qTb after F1

    dim3 gg(DD / 128, (BB * LL) / 128);    // (8, 128)  for i8 GEMMs
    dim3 g2(DD / 256, (BB * LL) / 256);    // (4, 64)   for 256^2 bf16 GEMMs

    // all conversions, one launch, 4 elems/thread, fully coalesced
    k_conv_all<<<53248, 256, 0, stream>>>(query, key, value, Wq, Wk, Wv, Wo,
                                          qxh, qxl, kxh, kxl, vxh,
                                          qwh, qwl, kwh, kwl, vwh, owh);
    // projections
    gemm_i8split<<<gg, 256, 0, stream>>>(qxh, qxl, qwh, qwl, bq, qTb);
    gemm_i8split<<<gg, 256, 0, stream>>>(kxh, kxl, kwh, kwl, bk, kTb);
    gemm_bf16_256<2><<<g2, 512, 131072, stream>>>(vxh, vwh, bv, nullptr, (float*)vbf);
    // autocorrelation
    fft_corr_partial<<<BB * HH * 8, 256, 0, stream>>>(qTb, kTb, part);
    fft_inv_topk<<<BB * HH, 256, 0, stream>>>(part, out + 16777216, topw, topi);
    gather_tr<<<BB * HH * 2, 256, 131072, stream>>>(vbf, topw, topi, aggrow);
    // output projection + residual
    gemm_bf16_256<1><<<g2, 512, 131072, stream>>>(aggrow, owh, bo, query, out);
}